// Round 7
// baseline (203.211 us; speedup 1.0000x reference)
//
#include <hip/hip_runtime.h>

#define NS  12
#define HID 128
#define SPB 8             // samples per block
#define RB  128           // rows per block = SPB*16

typedef __attribute__((ext_vector_type(8))) short bf8_t;   // 8 bf16 (4 VGPR)
typedef __attribute__((ext_vector_type(4))) float f4_t;    // C/D frag

// ws layout (u32 units): W0hi@0 (2048), W0lo@2048; W_i (i=1..3):
// hi @ 4096+(i-1)*16384 (8192), lo @ hi+8192.  Total 53248 u32 = 208 KB.
#define O_W0H 0
#define O_W0L 2048
#define O_WH(i) (4096 + (i) * 16384)
#define O_WL(i) (O_WH(i) + 8192)

__device__ __forceinline__ unsigned f2bf_u(float f) {
  unsigned u = __float_as_uint(f);
  return (u + 0x7FFFu + ((u >> 16) & 1u)) >> 16;     // RNE
}
__device__ __forceinline__ float bf2f(unsigned h) { return __uint_as_float(h << 16); }

// packed 2x f32 -> 2x bf16 (RNE). No builtin on gfx950 (T12 recipe) -> asm.
__device__ __forceinline__ unsigned cvtpk(float a, float b) {
  unsigned r;
  asm("v_cvt_pk_bf16_f32 %0, %1, %2" : "=v"(r) : "v"(a), "v"(b));
  return r;
}
__device__ __forceinline__ f4_t mfma16(bf8_t a, bf8_t b, f4_t c) {
  return __builtin_amdgcn_mfma_f32_16x16x32_bf16(a, b, c, 0, 0, 0);
}

// ---------------------------------------------------------------------------
// Prep (proven): bf16 hi/lo planes, fragment-order, u32 paired stores.
// ---------------------------------------------------------------------------
__global__ __launch_bounds__(256) void prep_w(
    const float* __restrict__ W0, const float* __restrict__ W1,
    const float* __restrict__ W2, const float* __restrict__ W3,
    unsigned* __restrict__ ws)
{
  int t = blockIdx.x * 256 + threadIdx.x;     // 104 tiles * 256 pair-slots
  if (t >= 26624) return;
  int tile = t >> 8;
  int pos  = (t & 255) * 2;                   // even element index in tile
  int g = pos >> 7, o = (pos >> 3) & 15, j = pos & 7;

  const float* src; int kdim; unsigned hoff, loff; int lt;
  if (tile < 8) { src = W0; kdim = NS; hoff = O_W0H; loff = O_W0L; lt = tile; }
  else {
    int li = (tile - 8) >> 5;  lt = (tile - 8) & 31;
    src = (li == 0) ? W1 : (li == 1) ? W2 : W3;
    kdim = HID; hoff = O_WH(li); loff = O_WL(li);
  }
  int ks = (tile < 8) ? 0 : (lt >> 3);
  int mt = (tile < 8) ? lt : (lt & 7);
  int k0 = ks * 32 + g * 8 + j;               // j even, k1 = k0+1
  int orow = mt * 16 + o;
  float v0 = (k0 < kdim)     ? src[orow * kdim + k0]     : 0.f;
  float v1 = (k0 + 1 < kdim) ? src[orow * kdim + k0 + 1] : 0.f;
  unsigned h0 = f2bf_u(v0), h1 = f2bf_u(v1);
  unsigned l0 = f2bf_u(v0 - bf2f(h0)), l1 = f2bf_u(v1 - bf2f(h1));
  int widx = (lt * 512 + pos) >> 1;           // u32 index
  (ws + hoff)[widx] = h0 | (h1 << 16);
  (ws + loff)[widx] = l0 | (l1 << 16);
}

// ---------------------------------------------------------------------------
// One layer: Sout = act(Sin @ W^T), double-buffered LDS (ONE barrier/layer).
// Sin/Sout: 8192-u32 hi plane + 8192-u32 lo plane (base, base+8192).
// TANH: tanh on V-row + (1-t^2) row-scaling of J rows; else bias-on-V only.
// Both modes write bf16 hi/lo split.
// ---------------------------------------------------------------------------
template<int KSUBS, bool TANH>
__device__ __forceinline__ void layer(
    const unsigned* __restrict__ Sin, unsigned* __restrict__ Sout,
    const unsigned* __restrict__ whi, const unsigned* __restrict__ wlo,
    const float* __restrict__ bias,
    int lane, int l15, int g, int bp, int rwave, int mwave, int mt0)
{
  f4_t acc[4][2];
  #pragma unroll
  for (int a = 0; a < 4; ++a)
    #pragma unroll
    for (int b = 0; b < 2; ++b) acc[a][b] = (f4_t){0.f, 0.f, 0.f, 0.f};

  const int aswz = (l15 & 7) << 2;        // row&7 == l15&7 for A rows

  bf8_t bh[2][2], bl[2][2];
  #pragma unroll
  for (int mm = 0; mm < 2; ++mm) {        // preload ks=0 B frags
    int tb = (mt0 + mm) * 256 + lane * 4;
    bh[0][mm] = __builtin_bit_cast(bf8_t, *(const uint4*)(whi + tb));
    bl[0][mm] = __builtin_bit_cast(bf8_t, *(const uint4*)(wlo + tb));
  }

  #pragma unroll
  for (int ks = 0; ks < KSUBS; ++ks) {
    const int cur = ks & 1, nxt = cur ^ 1;
    if (ks + 1 < KSUBS) {                 // prefetch next K-slice's B frags
      #pragma unroll
      for (int mm = 0; mm < 2; ++mm) {
        int tb = ((ks + 1) * 8 + mt0 + mm) * 256 + lane * 4;
        bh[nxt][mm] = __builtin_bit_cast(bf8_t, *(const uint4*)(whi + tb));
        bl[nxt][mm] = __builtin_bit_cast(bf8_t, *(const uint4*)(wlo + tb));
      }
    }
    #pragma unroll
    for (int rs = 0; rs < 4; ++rs) {
      int row = rwave + rs * 16 + l15;
      int idx = row * 64 + ((ks * 16 + g * 4) ^ aswz);
      bf8_t avh = __builtin_bit_cast(bf8_t, *(const uint4*)(Sin + idx));
      bf8_t avl = __builtin_bit_cast(bf8_t, *(const uint4*)(Sin + 8192 + idx));
      #pragma unroll
      for (int mm = 0; mm < 2; ++mm) {
        acc[rs][mm] = mfma16(avh, bh[cur][mm], acc[rs][mm]);
        acc[rs][mm] = mfma16(avh, bl[cur][mm], acc[rs][mm]);
        acc[rs][mm] = mfma16(avl, bh[cur][mm], acc[rs][mm]);
      }
    }
  }

  float bv[2];
  #pragma unroll
  for (int mm = 0; mm < 2; ++mm) bv[mm] = bias[mwave + mm * 16 + l15];

  // NO barrier here: Sout is a different buffer than any concurrent reader's.
  const bool ev = (lane & 1) == 0;
  #pragma unroll
  for (int rs = 0; rs < 4; ++rs) {
    int rb = rwave + rs * 16 + g * 4;
    int row0 = rb + (ev ? 0 : 2);        // this lane owns rows row0, row0+1
    int row1 = row0 + 1;
    int a0b = row0 * 64, sw0 = (row0 & 7) << 2;
    int a1b = row1 * 64, sw1 = (row1 & 7) << 2;
    #pragma unroll
    for (int mm = 0; mm < 2; ++mm) {
      f4_t a = acc[rs][mm];
      if (TANH) {
        float pre = a[0] + bv[mm];
        float vb = __int_as_float(__builtin_amdgcn_ds_bpermute(bp, __float_as_int(pre)));
        float e = __expf(fminf(vb, 15.f) * 2.f);
        float r = __builtin_amdgcn_rcpf(e + 1.f);
        float t = (e - 1.f) * r;
        float s = fmaf(-t, t, 1.f);
        a[0] = (g == 0) ? t : a[0] * s;
        a[1] *= s; a[2] *= s; a[3] *= s;
      } else {
        if (g == 0) a[0] += bv[mm];       // V row only
      }
      // pair adjacent columns across the lane pair (lane^1)
      float p0 = __shfl_xor(a[0], 1);
      float p1 = __shfl_xor(a[1], 1);
      float p2 = __shfl_xor(a[2], 1);
      float p3 = __shfl_xor(a[3], 1);
      float u0 = ev ? a[0] : p2;          // row0, even col
      float u1 = ev ? p0 : a[2];          // row0, odd col
      float v0 = ev ? a[1] : p3;          // row1, even col
      float v1 = ev ? p1 : a[3];          // row1, odd col
      int wc = (mwave + mm * 16) / 2 + (l15 >> 1);
      unsigned wh0 = cvtpk(u0, u1);
      float rl0 = u0 - __uint_as_float(wh0 << 16);
      float rh0 = u1 - __uint_as_float(wh0 & 0xFFFF0000u);
      unsigned wl0 = cvtpk(rl0, rh0);
      unsigned wh1 = cvtpk(v0, v1);
      float rl1 = v0 - __uint_as_float(wh1 << 16);
      float rh1 = v1 - __uint_as_float(wh1 & 0xFFFF0000u);
      unsigned wl1 = cvtpk(rl1, rh1);
      int i0 = a0b + (wc ^ sw0);
      int i1 = a1b + (wc ^ sw1);
      Sout[i0] = wh0;  Sout[8192 + i0] = wl0;
      Sout[i1] = wh1;  Sout[8192 + i1] = wl1;
    }
  }
  __syncthreads();   // writes visible before next layer reads Sout
}

__global__ __launch_bounds__(512, 4) void mlp_jac(
    const float* __restrict__ state,
    const float* __restrict__ safe_m, const float* __restrict__ safe_l,
    const unsigned* __restrict__ ws,
    const float* __restrict__ b0, const float* __restrict__ b1,
    const float* __restrict__ b2, const float* __restrict__ b3,
    const float* __restrict__ Wout, const float* __restrict__ bout,
    float* __restrict__ out, int bs)
{
  __shared__ unsigned S[2][16384];  // 2 x (hi plane | lo plane), 64 KB total
  __shared__ float red[512];        // 2 KB

  const int tid  = threadIdx.x;
  const int lane = tid & 63;
  const int wid  = tid >> 6;
  const int widR = wid >> 2;          // 0..1: 64-row half
  const int widN = wid & 3;           // 0..3: 32-col group
  const int rwave = widR * 64;
  const int mwave = widN * 32;
  const int mt0   = widN * 2;
  const int l15 = lane & 15;
  const int g   = lane >> 4;
  const int bp  = l15 * 4;
  const int s0  = blockIdx.x * SPB;

  // ---- build X0 (into S[0]): rows 16b+0 = x_norm, 16b+(1..12) = diag(1/rng)
  for (int i = tid; i < RB * 16; i += 512) {
    int r = i >> 4, kp = i & 15;
    int b = r >> 4, rr = r & 15;
    int sidx = s0 + b;
    float v[2];
    #pragma unroll
    for (int t = 0; t < 2; ++t) {
      int k = kp * 2 + t;
      float val = 0.f;
      if (k < NS) {
        float m = safe_m[k], l = safe_l[k];
        float inv = 2.f / (m - l);
        if (rr == 0) {
          float sv = (sidx < bs) ? state[sidx * NS + k] : 0.f;
          val = (sv - 0.5f * (m + l)) * inv;
        } else if (k == rr - 1) val = inv;
      }
      v[t] = val;
    }
    unsigned wh = cvtpk(v[0], v[1]);
    float rl = v[0] - __uint_as_float(wh << 16);
    float rh = v[1] - __uint_as_float(wh & 0xFFFF0000u);
    unsigned wl = cvtpk(rl, rh);
    int idx = r * 64 + (kp ^ ((r & 7) << 2));
    S[0][idx] = wh;
    S[0][8192 + idx] = wl;
  }
  __syncthreads();

  layer<1, true >(S[0], S[1], ws + O_W0H,  ws + O_W0L,  b0, lane, l15, g, bp, rwave, mwave, mt0);
  layer<4, true >(S[1], S[0], ws + O_WH(0), ws + O_WL(0), b1, lane, l15, g, bp, rwave, mwave, mt0);
  layer<4, true >(S[0], S[1], ws + O_WH(1), ws + O_WL(1), b2, lane, l15, g, bp, rwave, mwave, mt0);
  layer<4, false>(S[1], S[0], ws + O_WH(2), ws + O_WL(2), b3, lane, l15, g, bp, rwave, mwave, mt0);

  // ---- out = Wout . X4[r,:] (+ bout on V rows); 4 threads per row
  {
    int r = tid & 127;
    int q = tid >> 7;                 // wave-uniform -> Wout via s_load
    int sw = (r & 7) << 2;
    float a = 0.f;
    #pragma unroll
    for (int kk = 0; kk < 8; ++kk) {
      int c = q * 32 + kk * 4;         // 4 columns
      int idx = r * 64 + ((c >> 1) ^ sw);
      uint2 h = *(const uint2*)(&S[0][idx]);
      uint2 lo = *(const uint2*)(&S[0][8192 + idx]);
      float x0 = __uint_as_float(h.x << 16)         + __uint_as_float(lo.x << 16);
      float x1 = __uint_as_float(h.x & 0xFFFF0000u) + __uint_as_float(lo.x & 0xFFFF0000u);
      float x2 = __uint_as_float(h.y << 16)         + __uint_as_float(lo.y << 16);
      float x3 = __uint_as_float(h.y & 0xFFFF0000u) + __uint_as_float(lo.y & 0xFFFF0000u);
      a = fmaf(Wout[c + 0], x0, a);
      a = fmaf(Wout[c + 1], x1, a);
      a = fmaf(Wout[c + 2], x2, a);
      a = fmaf(Wout[c + 3], x3, a);
    }
    red[tid] = a;
  }
  __syncthreads();
  if (tid < 128) {
    float tot = red[tid] + red[tid + 128] + red[tid + 256] + red[tid + 384];
    int b = tid >> 4, rr = tid & 15;
    int sidx = s0 + b;
    if (sidx < bs && rr < 13) {
      if (rr == 0) tot += bout[0];
      out[sidx * 13 + rr] = tot;
    }
  }
}

extern "C" void kernel_launch(void* const* d_in, const int* in_sizes, int n_in,
                              void* d_out, int out_size, void* d_ws, size_t ws_size,
                              hipStream_t stream)
{
  const float* state  = (const float*)d_in[0];
  const float* safe_m = (const float*)d_in[1];
  const float* safe_l = (const float*)d_in[2];
  const float* W0   = (const float*)d_in[3];
  const float* b0   = (const float*)d_in[4];
  const float* W1   = (const float*)d_in[5];
  const float* b1   = (const float*)d_in[6];
  const float* W2   = (const float*)d_in[7];
  const float* b2   = (const float*)d_in[8];
  const float* W3   = (const float*)d_in[9];
  const float* b3   = (const float*)d_in[10];
  const float* Wout = (const float*)d_in[11];
  const float* bout = (const float*)d_in[12];
  unsigned* ws = (unsigned*)d_ws;
  float* out = (float*)d_out;

  const int bs = in_sizes[0] / NS;     // 16384

  prep_w<<<104, 256, 0, stream>>>(W0, W1, W2, W3, ws);

  const int nblocks = (bs + SPB - 1) / SPB;   // 2048
  mlp_jac<<<nblocks, 512, 0, stream>>>(state, safe_m, safe_l, ws,
      b0, b1, b2, b3, Wout, bout, out, bs);
}

// Round 8
// 175.217 us; speedup vs baseline: 1.1598x; 1.1598x over previous
//
#include <hip/hip_runtime.h>

#define NS  12
#define HID 128
#define SPB 4             // samples per block
#define RB  64            // rows per block = SPB*16

typedef __attribute__((ext_vector_type(8)))  short bf8_t;   // 8 bf16 (4 VGPR)
typedef __attribute__((ext_vector_type(16))) float f16f;    // 32x32 C/D frag

// ws layout (u32 units): W0hi@0 (1024), W0lo@1024; W_i (i=1..3):
// hi @ 2048+(i-1)*16384 (8192 u32), lo @ hi+8192.  Total 51200 u32 = 200 KB.
#define O_W0H 0
#define O_W0L 1024
#define O_WH(i) (2048 + (i) * 16384)
#define O_WL(i) (O_WH(i) + 8192)

__device__ __forceinline__ unsigned f2bf_u(float f) {
  unsigned u = __float_as_uint(f);
  return (u + 0x7FFFu + ((u >> 16) & 1u)) >> 16;     // RNE
}
__device__ __forceinline__ float bf2f(unsigned h) { return __uint_as_float(h << 16); }

// packed 2x f32 -> 2x bf16 (RNE). No builtin on gfx950 (T12 recipe) -> asm.
__device__ __forceinline__ unsigned cvtpk(float a, float b) {
  unsigned r;
  asm("v_cvt_pk_bf16_f32 %0, %1, %2" : "=v"(r) : "v"(a), "v"(b));
  return r;
}
__device__ __forceinline__ f16f mfma32(bf8_t a, bf8_t b, f16f c) {
  return __builtin_amdgcn_mfma_f32_32x32x16_bf16(a, b, c, 0, 0, 0);
}

// ---------------------------------------------------------------------------
// Prep: bf16 hi/lo planes, 32x32x16 B-fragment order.
// Tile (ks, nt): 512 bf16; lane l's 16B at base + l*16 holds
// W[n = nt*32 + (l&31)][k = ks*16 + (l>>5)*8 + j], j=0..7.  W0: K padded to 16.
// ---------------------------------------------------------------------------
__global__ __launch_bounds__(256) void prep_w(
    const float* __restrict__ W0, const float* __restrict__ W1,
    const float* __restrict__ W2, const float* __restrict__ W3,
    unsigned* __restrict__ ws)
{
  int t = blockIdx.x * 256 + threadIdx.x;     // 100 tiles * 256 pair-slots
  if (t >= 25600) return;
  int tile = t >> 8;
  int pos  = (t & 255) * 2;                   // even element index in tile
  int ln = pos >> 3, j = pos & 7;             // j even

  const float* src; int kdim; unsigned hoff, loff; int lt;
  if (tile < 4) { src = W0; kdim = NS; hoff = O_W0H; loff = O_W0L; lt = tile; }
  else {
    int li = (tile - 4) >> 5;  lt = (tile - 4) & 31;
    src = (li == 0) ? W1 : (li == 1) ? W2 : W3;
    kdim = HID; hoff = O_WH(li); loff = O_WL(li);
  }
  int ks = (tile < 4) ? 0 : (lt >> 2);
  int nt = (tile < 4) ? lt : (lt & 3);
  int k0 = ks * 16 + (ln >> 5) * 8 + j;       // j even, k1 = k0+1
  int n  = nt * 32 + (ln & 31);
  float v0 = (k0 < kdim)     ? src[n * kdim + k0]     : 0.f;
  float v1 = (k0 + 1 < kdim) ? src[n * kdim + k0 + 1] : 0.f;
  unsigned h0 = f2bf_u(v0), h1 = f2bf_u(v1);
  unsigned l0 = f2bf_u(v0 - bf2f(h0)), l1 = f2bf_u(v1 - bf2f(h1));
  int widx = (lt * 512 + pos) >> 1;           // u32 index
  (ws + hoff)[widx] = h0 | (h1 << 16);
  (ws + loff)[widx] = l0 | (l1 << 16);
}

// ---------------------------------------------------------------------------
// One layer (in-place X buffer, 2 barriers): X' = act(X @ W^T).
// X planes: S[0..4096) hi, S[4096..8192) lo; word = 2 cols; row stride 64 u32;
// swizzle: word w of row r stored at w ^ ((r&15)<<2).
// Each of 4 waves owns 32 cols (nt) x all 64 rows (2 row-tiles of 32).
// TANH=false: last layer, writes f32 [64][128] into S (float4-granule swizzle).
// ---------------------------------------------------------------------------
template<int KSUBS, bool TANH>
__device__ __forceinline__ void layer(
    unsigned* __restrict__ S,
    const unsigned* __restrict__ whi, const unsigned* __restrict__ wlo,
    const float* __restrict__ bias, int l31, int g2, int nt, int bp)
{
  f16f acc[2] = {};
  const int lane = g2 * 32 + l31;
  const int srm = (l31 & 15) << 2;            // A-row swizzle (m&15 == l31&15)

  bf8_t bh[2], bl[2];
  {
    int tb = nt * 256 + lane * 4;
    bh[0] = __builtin_bit_cast(bf8_t, *(const uint4*)(whi + tb));
    bl[0] = __builtin_bit_cast(bf8_t, *(const uint4*)(wlo + tb));
  }

  #pragma unroll
  for (int ks = 0; ks < KSUBS; ++ks) {
    const int cur = ks & 1, nxt = cur ^ 1;
    if (ks + 1 < KSUBS) {                     // prefetch next K-slice B frags
      int tb = ((ks + 1) * 4 + nt) * 256 + lane * 4;
      bh[nxt] = __builtin_bit_cast(bf8_t, *(const uint4*)(whi + tb));
      bl[nxt] = __builtin_bit_cast(bf8_t, *(const uint4*)(wlo + tb));
    }
    #pragma unroll
    for (int rt = 0; rt < 2; ++rt) {
      int m = rt * 32 + l31;
      int idx = m * 64 + ((ks * 8 + g2 * 4) ^ srm);
      bf8_t avh = __builtin_bit_cast(bf8_t, *(const uint4*)(S + idx));
      bf8_t avl = __builtin_bit_cast(bf8_t, *(const uint4*)(S + 4096 + idx));
      acc[rt] = mfma32(avh, bh[cur], acc[rt]);
      acc[rt] = mfma32(avh, bl[cur], acc[rt]);
      acc[rt] = mfma32(avl, bh[cur], acc[rt]);
    }
  }

  const float bv = bias[nt * 32 + l31];
  __syncthreads();                            // all reads done -> overwrite ok

  const bool ev = (l31 & 1) == 0;
  const int wcb = nt * 16 + (l31 >> 1);
  #pragma unroll
  for (int rt = 0; rt < 2; ++rt) {
    float t0, s0, t1, s1;
    if (TANH) {
      // V rows (tile-rows 0 and 16) live in reg0/reg8 of g2==0 lanes
      float pre0 = acc[rt][0] + bv;
      float pre8 = acc[rt][8] + bv;
      float vb0 = __int_as_float(__builtin_amdgcn_ds_bpermute(bp, __float_as_int(pre0)));
      float vb8 = __int_as_float(__builtin_amdgcn_ds_bpermute(bp, __float_as_int(pre8)));
      float e0 = __expf(fminf(vb0, 15.f) * 2.f);
      t0 = (e0 - 1.f) * __builtin_amdgcn_rcpf(e0 + 1.f);
      s0 = fmaf(-t0, t0, 1.f);
      float e1 = __expf(fminf(vb8, 15.f) * 2.f);
      t1 = (e1 - 1.f) * __builtin_amdgcn_rcpf(e1 + 1.f);
      s1 = fmaf(-t1, t1, 1.f);
    }
    #pragma unroll
    for (int reg = 0; reg < 16; ++reg) {
      float a = acc[rt][reg];
      float v;
      if (TANH) {
        float ss = (reg < 8) ? s0 : s1;
        float tt = (reg < 8) ? t0 : t1;
        v = ((reg & 7) == 0) ? ((g2 == 0) ? tt : a * ss) : a * ss;
      } else {
        v = ((reg & 7) == 0) ? ((g2 == 0) ? a + bv : a) : a;
      }
      int r = rt * 32 + (reg & 3) + 8 * (reg >> 2) + 4 * g2;
      if (TANH) {
        float p = __shfl_xor(v, 1);           // partner col (adjacent lane)
        if ((reg & 1) == (l31 & 1)) {         // each lane stores 8 of 16 words
          float vlo = ev ? v : p;
          float vhi = ev ? p : v;
          unsigned wh = cvtpk(vlo, vhi);
          float rl = vlo - __uint_as_float(wh << 16);
          float rh = vhi - __uint_as_float(wh & 0xFFFF0000u);
          unsigned wl = cvtpk(rl, rh);
          int idx = r * 64 + (wcb ^ ((r & 15) << 2));
          S[idx] = wh;  S[4096 + idx] = wl;
        }
      } else {
        float* Xf = (float*)S;
        int c = nt * 32 + l31;
        int idx = r * 128 + ((c & ~3) ^ ((r & 31) << 2)) + (c & 3);
        Xf[idx] = v;
      }
    }
  }
  __syncthreads();
}

__global__ __launch_bounds__(256, 4) void mlp_jac(
    const float* __restrict__ state,
    const float* __restrict__ safe_m, const float* __restrict__ safe_l,
    const unsigned* __restrict__ ws,
    const float* __restrict__ b0, const float* __restrict__ b1,
    const float* __restrict__ b2, const float* __restrict__ b3,
    const float* __restrict__ Wout, const float* __restrict__ bout,
    float* __restrict__ out, int bs)
{
  __shared__ unsigned S[8192];    // 32 KB: hi|lo bf16 planes, or [64][128] f32
  __shared__ float red[256];      // 1 KB

  const int tid  = threadIdx.x;
  const int lane = tid & 63;
  const int nt   = tid >> 6;          // wave id = col tile (32 cols)
  const int l31  = lane & 31;
  const int g2   = lane >> 5;
  const int bp   = l31 << 2;          // bpermute: read lane l31 (g2=0 group)
  const int s0   = blockIdx.x * SPB;

  // ---- build X0 words 0..7 (cols 0..15): rows 16b+0 = x_norm,
  //      16b+(1..12) = diag(1/x_range), rest zero
  for (int i = tid; i < RB * 8; i += 256) {
    int r = i >> 3, kp = i & 7;
    int b = r >> 4, rr = r & 15;
    int sidx = s0 + b;
    float v[2];
    #pragma unroll
    for (int t = 0; t < 2; ++t) {
      int k = kp * 2 + t;
      float val = 0.f;
      if (k < NS) {
        float m = safe_m[k], l = safe_l[k];
        float inv = 2.f / (m - l);
        if (rr == 0) {
          float sv = (sidx < bs) ? state[sidx * NS + k] : 0.f;
          val = (sv - 0.5f * (m + l)) * inv;
        } else if (k == rr - 1) val = inv;
      }
      v[t] = val;
    }
    unsigned wh = cvtpk(v[0], v[1]);
    float rl = v[0] - __uint_as_float(wh << 16);
    float rh = v[1] - __uint_as_float(wh & 0xFFFF0000u);
    unsigned wl = cvtpk(rl, rh);
    int idx = r * 64 + (kp ^ ((r & 15) << 2));
    S[idx] = wh;
    S[4096 + idx] = wl;
  }
  __syncthreads();

  layer<1, true >(S, ws + O_W0H,   ws + O_W0L,   b0, l31, g2, nt, bp);
  layer<8, true >(S, ws + O_WH(0), ws + O_WL(0), b1, l31, g2, nt, bp);
  layer<8, true >(S, ws + O_WH(1), ws + O_WL(1), b2, l31, g2, nt, bp);
  layer<8, false>(S, ws + O_WH(2), ws + O_WL(2), b3, l31, g2, nt, bp);

  // ---- out = Wout . X4[r,:] (+ bout on V rows); 4 threads per row
  {
    const float* Xf = (const float*)S;
    int r = tid & 63;
    int q = tid >> 6;                 // wave-uniform -> Wout via s_load
    int sw = (r & 31) << 2;
    float a = 0.f;
    #pragma unroll
    for (int kk = 0; kk < 8; ++kk) {
      int c = q * 32 + kk * 4;
      const float4 x = *(const float4*)(Xf + r * 128 + (c ^ sw));
      a = fmaf(Wout[c + 0], x.x, a);
      a = fmaf(Wout[c + 1], x.y, a);
      a = fmaf(Wout[c + 2], x.z, a);
      a = fmaf(Wout[c + 3], x.w, a);
    }
    red[tid] = a;
  }
  __syncthreads();
  if (tid < 64) {
    float tot = red[tid] + red[tid + 64] + red[tid + 128] + red[tid + 192];
    int b = tid >> 4, rr = tid & 15;
    int sidx = s0 + b;
    if (sidx < bs && rr < 13) {
      if (rr == 0) tot += bout[0];
      out[sidx * 13 + rr] = tot;
    }
  }
}

extern "C" void kernel_launch(void* const* d_in, const int* in_sizes, int n_in,
                              void* d_out, int out_size, void* d_ws, size_t ws_size,
                              hipStream_t stream)
{
  const float* state  = (const float*)d_in[0];
  const float* safe_m = (const float*)d_in[1];
  const float* safe_l = (const float*)d_in[2];
  const float* W0   = (const float*)d_in[3];
  const float* b0   = (const float*)d_in[4];
  const float* W1   = (const float*)d_in[5];
  const float* b1   = (const float*)d_in[6];
  const float* W2   = (const float*)d_in[7];
  const float* b2   = (const float*)d_in[8];
  const float* W3   = (const float*)d_in[9];
  const float* b3   = (const float*)d_in[10];
  const float* Wout = (const float*)d_in[11];
  const float* bout = (const float*)d_in[12];
  unsigned* ws = (unsigned*)d_ws;
  float* out = (float*)d_out;

  const int bs = in_sizes[0] / NS;     // 16384

  prep_w<<<100, 256, 0, stream>>>(W0, W1, W2, W3, ws);

  const int nblocks = (bs + SPB - 1) / SPB;   // 4096
  mlp_jac<<<nblocks, 256, 0, stream>>>(state, safe_m, safe_l, ws,
      b0, b1, b2, b3, Wout, bout, out, bs);
}

// Round 9
// 162.369 us; speedup vs baseline: 1.2515x; 1.0791x over previous
//
#include <hip/hip_runtime.h>

#define NS  12
#define HID 128
#define SPB 4             // samples per block
#define RB  64            // rows per block = SPB*16

typedef __attribute__((ext_vector_type(8)))  short bf8_t;   // 8 bf16 (4 VGPR)
typedef __attribute__((ext_vector_type(16))) float f16f;    // 32x32 C/D frag

// ws layout (u32 units): W0hi@0 (1024), W0lo@1024; W_i (i=1..3):
// hi @ 2048+(i-1)*16384 (8192 u32), lo @ hi+8192.  Total 51200 u32 = 200 KB.
#define O_W0H 0
#define O_W0L 1024
#define O_WH(i) (2048 + (i) * 16384)
#define O_WL(i) (O_WH(i) + 8192)

__device__ __forceinline__ unsigned f2bf_u(float f) {
  unsigned u = __float_as_uint(f);
  return (u + 0x7FFFu + ((u >> 16) & 1u)) >> 16;     // RNE
}
__device__ __forceinline__ float bf2f(unsigned h) { return __uint_as_float(h << 16); }

// packed 2x f32 -> 2x bf16 (RNE). No builtin on gfx950 (T12 recipe) -> asm.
__device__ __forceinline__ unsigned cvtpk(float a, float b) {
  unsigned r;
  asm("v_cvt_pk_bf16_f32 %0, %1, %2" : "=v"(r) : "v"(a), "v"(b));
  return r;
}
__device__ __forceinline__ f16f mfma32(bf8_t a, bf8_t b, f16f c) {
  return __builtin_amdgcn_mfma_f32_32x32x16_bf16(a, b, c, 0, 0, 0);
}

// ---------------------------------------------------------------------------
// Prep (proven round 8): bf16 hi/lo planes, 32x32x16 B-fragment order.
// Tile (ks, nt): 512 bf16; lane l's 16B at base + l*16 holds
// W[n = nt*32 + (l&31)][k = ks*16 + (l>>5)*8 + j], j=0..7.  W0: K padded to 16.
// ---------------------------------------------------------------------------
__global__ __launch_bounds__(256) void prep_w(
    const float* __restrict__ W0, const float* __restrict__ W1,
    const float* __restrict__ W2, const float* __restrict__ W3,
    unsigned* __restrict__ ws)
{
  int t = blockIdx.x * 256 + threadIdx.x;     // 100 tiles * 256 pair-slots
  if (t >= 25600) return;
  int tile = t >> 8;
  int pos  = (t & 255) * 2;                   // even element index in tile
  int ln = pos >> 3, j = pos & 7;             // j even

  const float* src; int kdim; unsigned hoff, loff; int lt;
  if (tile < 4) { src = W0; kdim = NS; hoff = O_W0H; loff = O_W0L; lt = tile; }
  else {
    int li = (tile - 4) >> 5;  lt = (tile - 4) & 31;
    src = (li == 0) ? W1 : (li == 1) ? W2 : W3;
    kdim = HID; hoff = O_WH(li); loff = O_WL(li);
  }
  int ks = (tile < 4) ? 0 : (lt >> 2);
  int nt = (tile < 4) ? lt : (lt & 3);
  int k0 = ks * 16 + (ln >> 5) * 8 + j;       // j even, k1 = k0+1
  int n  = nt * 32 + (ln & 31);
  float v0 = (k0 < kdim)     ? src[n * kdim + k0]     : 0.f;
  float v1 = (k0 + 1 < kdim) ? src[n * kdim + k0 + 1] : 0.f;
  unsigned h0 = f2bf_u(v0), h1 = f2bf_u(v1);
  unsigned l0 = f2bf_u(v0 - bf2f(h0)), l1 = f2bf_u(v1 - bf2f(h1));
  int widx = (lt * 512 + pos) >> 1;           // u32 index
  (ws + hoff)[widx] = h0 | (h1 << 16);
  (ws + loff)[widx] = l0 | (l1 << 16);
}

// ---------------------------------------------------------------------------
// One layer, in-place S, 2 barriers — but ALL epilogue compute happens
// BEFORE bar1 (register-only); between bar1/bar2 only ds_writes with
// precomputed XOR-base + compile-time offset immediates.
// S planes: [0..4096) hi words, [4096..8192) lo words; word = 2 cols;
// row stride 64 words; word w of row r at w ^ ((r&15)<<2).
// ---------------------------------------------------------------------------
template<int KSUBS, bool TANH>
__device__ __forceinline__ void layer(
    unsigned* __restrict__ S,
    const unsigned* __restrict__ whi, const unsigned* __restrict__ wlo,
    const float* __restrict__ bias, int l31, int g2, int nt, int bp)
{
  const float bv = bias[nt * 32 + l31];       // hoisted (latency hidden by MFMA)
  f16f acc[2] = {};

  const int srm   = (l31 & 15) << 2;
  const int base0 = (l31 << 6) ^ (g2 << 2) ^ srm;   // A-read words, rt=0
  const int lane4 = (g2 * 32 + l31) * 4;

  bf8_t bh[2], bl[2];
  {
    int tb = nt * 256 + lane4;
    bh[0] = __builtin_bit_cast(bf8_t, *(const uint4*)(whi + tb));
    bl[0] = __builtin_bit_cast(bf8_t, *(const uint4*)(wlo + tb));
  }

  #pragma unroll
  for (int ks = 0; ks < KSUBS; ++ks) {
    const int cur = ks & 1, nxt = cur ^ 1;
    if (ks + 1 < KSUBS) {                     // prefetch next K-slice B frags
      int tb = ((ks + 1) * 4 + nt) * 256 + lane4;
      bh[nxt] = __builtin_bit_cast(bf8_t, *(const uint4*)(whi + tb));
      bl[nxt] = __builtin_bit_cast(bf8_t, *(const uint4*)(wlo + tb));
    }
    #pragma unroll
    for (int rt = 0; rt < 2; ++rt) {
      int idx = (base0 + rt * 2048) ^ (ks * 8);   // +2048 keeps low bits ^-safe
      bf8_t avh = __builtin_bit_cast(bf8_t, *(const uint4*)(S + idx));
      bf8_t avl = __builtin_bit_cast(bf8_t, *(const uint4*)(S + 4096 + idx));
      acc[rt] = mfma32(avh, bh[cur], acc[rt]);
      acc[rt] = mfma32(avh, bl[cur], acc[rt]);
      acc[rt] = mfma32(avl, bh[cur], acc[rt]);
    }
  }

  // D layout: col = nt*32+l31, row = rt*32 + (reg&3) + 8*(reg>>2) + 4*g2.
  if (TANH) {
    const int par = l31 & 1;
    const int wcb = nt * 16 + (l31 >> 1);
    // store byte-addr = Qb ^ ((K0&15)<<4)  +  offset:((rt*32+K0)*256 [+16384])
    const unsigned Qb = (unsigned)(par * 256 + g2 * 1024 +
                        ((wcb << 2) ^ (par << 4) ^ (g2 << 6)));
    unsigned st[2][16];
    #pragma unroll
    for (int rt = 0; rt < 2; ++rt) {
      // V rows (m_local 0,16) live in reg 0 / reg 8 of g2==0 lanes
      float pre0 = acc[rt][0] + bv;
      float pre8 = acc[rt][8] + bv;
      float vb0 = __int_as_float(__builtin_amdgcn_ds_bpermute(bp, __float_as_int(pre0)));
      float vb8 = __int_as_float(__builtin_amdgcn_ds_bpermute(bp, __float_as_int(pre8)));
      // tanh: r = rcp(2^(2x*log2e)+1); t = 1-2r; s = 1-t^2.  Clamp-free, inf-safe.
      float e0 = exp2f(vb0 * 2.885390082f);
      float r0 = __builtin_amdgcn_rcpf(e0 + 1.f);
      float t0 = fmaf(-2.f, r0, 1.f);
      float s0 = fmaf(-t0, t0, 1.f);
      float e1 = exp2f(vb8 * 2.885390082f);
      float r1 = __builtin_amdgcn_rcpf(e1 + 1.f);
      float t1 = fmaf(-2.f, r1, 1.f);
      float s1 = fmaf(-t1, t1, 1.f);
      float v[16], p[16];
      #pragma unroll
      for (int reg = 0; reg < 16; ++reg) {
        float a  = acc[rt][reg];
        float ss = (reg < 8) ? s0 : s1;
        float tt = (reg < 8) ? t0 : t1;
        float val = a * ss;
        if ((reg & 7) == 0) val = (g2 == 0) ? tt : val;   // V row -> tanh
        v[reg] = val;
      }
      #pragma unroll
      for (int reg = 0; reg < 16; ++reg) p[reg] = __shfl_xor(v[reg], 1);
      #pragma unroll
      for (int j = 0; j < 8; ++j) {
        // lane stores rows reg = 2j+par; word = (even col, odd col)
        float ecol = par ? p[2 * j + 1] : v[2 * j];
        float ocol = par ? v[2 * j + 1] : p[2 * j];
        unsigned hw = cvtpk(ecol, ocol);
        float rl = ecol - __uint_as_float(hw << 16);
        float rh = ocol - __uint_as_float(hw & 0xFFFF0000u);
        st[rt][j]     = hw;
        st[rt][8 + j] = cvtpk(rl, rh);
      }
    }
    __builtin_amdgcn_sched_barrier(0);        // pin epi-compute before barrier
    __syncthreads();                          // all reads of S done
    char* Sb = (char*)S;
    #pragma unroll
    for (int j = 0; j < 8; ++j) {
      const int K0 = ((2 * j) & 3) + 8 * (j >> 1);    // 0,2,8,10,16,18,24,26
      unsigned a = Qb ^ (unsigned)((K0 & 15) << 4);
      #pragma unroll
      for (int rt = 0; rt < 2; ++rt) {
        *(unsigned*)(Sb + a + (rt * 32 + K0) * 256)         = st[rt][j];
        *(unsigned*)(Sb + a + (rt * 32 + K0) * 256 + 16384) = st[rt][8 + j];
      }
    }
    __syncthreads();
  } else {
    // last layer: f32 [64][128], word w of row r at (c&~3)^((r&31)<<2) | c&3
    #pragma unroll
    for (int rt = 0; rt < 2; ++rt)
      if (g2 == 0) { acc[rt][0] += bv; acc[rt][8] += bv; }   // bias on V rows
    const int c = nt * 32 + l31;
    const unsigned Qf = (unsigned)(g2 * 2048 +
        ((((c & ~3) << 2) ^ (g2 << 6)) + ((c & 3) << 2)));
    __builtin_amdgcn_sched_barrier(0);
    __syncthreads();
    char* Sb = (char*)S;
    #pragma unroll
    for (int reg = 0; reg < 16; ++reg) {
      const int K = (reg & 3) + 8 * (reg >> 2);
      unsigned a = Qf ^ (unsigned)(K << 4);
      #pragma unroll
      for (int rt = 0; rt < 2; ++rt)
        *(float*)(Sb + a + (rt * 32 + K) * 512) = acc[rt][reg];
    }
    __syncthreads();
  }
}

__global__ __launch_bounds__(256, 4) void mlp_jac(
    const float* __restrict__ state,
    const float* __restrict__ safe_m, const float* __restrict__ safe_l,
    const unsigned* __restrict__ ws,
    const float* __restrict__ b0, const float* __restrict__ b1,
    const float* __restrict__ b2, const float* __restrict__ b3,
    const float* __restrict__ Wout, const float* __restrict__ bout,
    float* __restrict__ out, int bs)
{
  __shared__ unsigned S[8192];    // 32 KB: hi|lo bf16 planes, or [64][128] f32
  __shared__ float red[256];      // 1 KB

  const int tid  = threadIdx.x;
  const int lane = tid & 63;
  const int nt   = tid >> 6;          // wave id = col tile (32 cols)
  const int l31  = lane & 31;
  const int g2   = lane >> 5;
  const int bp   = l31 << 2;          // bpermute: read lane l31 (g2=0 copy)
  const int s0   = blockIdx.x * SPB;

  // ---- build X0 words 0..7 (cols 0..15): rows 16b+0 = x_norm,
  //      16b+(1..12) = diag(1/x_range), rest zero
  for (int i = tid; i < RB * 8; i += 256) {
    int r = i >> 3, kp = i & 7;
    int b = r >> 4, rr = r & 15;
    int sidx = s0 + b;
    float v[2];
    #pragma unroll
    for (int t = 0; t < 2; ++t) {
      int k = kp * 2 + t;
      float val = 0.f;
      if (k < NS) {
        float m = safe_m[k], l = safe_l[k];
        float inv = 2.f / (m - l);
        if (rr == 0) {
          float sv = (sidx < bs) ? state[sidx * NS + k] : 0.f;
          val = (sv - 0.5f * (m + l)) * inv;
        } else if (k == rr - 1) val = inv;
      }
      v[t] = val;
    }
    unsigned wh = cvtpk(v[0], v[1]);
    float rl = v[0] - __uint_as_float(wh << 16);
    float rh = v[1] - __uint_as_float(wh & 0xFFFF0000u);
    unsigned wl = cvtpk(rl, rh);
    int idx = r * 64 + (kp ^ ((r & 15) << 2));
    S[idx] = wh;
    S[4096 + idx] = wl;
  }
  __syncthreads();

  layer<1, true >(S, ws + O_W0H,   ws + O_W0L,   b0, l31, g2, nt, bp);
  layer<8, true >(S, ws + O_WH(0), ws + O_WL(0), b1, l31, g2, nt, bp);
  layer<8, true >(S, ws + O_WH(1), ws + O_WL(1), b2, l31, g2, nt, bp);
  layer<8, false>(S, ws + O_WH(2), ws + O_WL(2), b3, l31, g2, nt, bp);

  // ---- out = Wout . X4[r,:] (+ bout on V rows); 4 threads per row
  {
    const float* Xf = (const float*)S;
    int r = tid & 63;
    int q = tid >> 6;                 // wave-uniform -> Wout via s_load
    int sw = (r & 31) << 2;
    float a = 0.f;
    #pragma unroll
    for (int kk = 0; kk < 8; ++kk) {
      int c = q * 32 + kk * 4;
      const float4 x = *(const float4*)(Xf + r * 128 + (c ^ sw));
      a = fmaf(Wout[c + 0], x.x, a);
      a = fmaf(Wout[c + 1], x.y, a);
      a = fmaf(Wout[c + 2], x.z, a);
      a = fmaf(Wout[c + 3], x.w, a);
    }
    red[tid] = a;
  }
  __syncthreads();
  if (tid < 64) {
    float tot = red[tid] + red[tid + 64] + red[tid + 128] + red[tid + 192];
    int b = tid >> 4, rr = tid & 15;
    int sidx = s0 + b;
    if (sidx < bs && rr < 13) {
      if (rr == 0) tot += bout[0];
      out[sidx * 13 + rr] = tot;
    }
  }
}

extern "C" void kernel_launch(void* const* d_in, const int* in_sizes, int n_in,
                              void* d_out, int out_size, void* d_ws, size_t ws_size,
                              hipStream_t stream)
{
  const float* state  = (const float*)d_in[0];
  const float* safe_m = (const float*)d_in[1];
  const float* safe_l = (const float*)d_in[2];
  const float* W0   = (const float*)d_in[3];
  const float* b0   = (const float*)d_in[4];
  const float* W1   = (const float*)d_in[5];
  const float* b1   = (const float*)d_in[6];
  const float* W2   = (const float*)d_in[7];
  const float* b2   = (const float*)d_in[8];
  const float* W3   = (const float*)d_in[9];
  const float* b3   = (const float*)d_in[10];
  const float* Wout = (const float*)d_in[11];
  const float* bout = (const float*)d_in[12];
  unsigned* ws = (unsigned*)d_ws;
  float* out = (float*)d_out;

  const int bs = in_sizes[0] / NS;     // 16384

  prep_w<<<100, 256, 0, stream>>>(W0, W1, W2, W3, ws);

  const int nblocks = (bs + SPB - 1) / SPB;   // 4096
  mlp_jac<<<nblocks, 256, 0, stream>>>(state, safe_m, safe_l, ws,
      b0, b1, b2, b3, Wout, bout, out, bs);
}